// Round 2
// baseline (817.478 us; speedup 1.0000x reference)
//
#include <hip/hip_runtime.h>
#include <hip/hip_bf16.h>
#include <math.h>

#define N_NODES 50000
#define M_PAD   50048           // 782 * 64 rows
#define E_EDGES 800000
#define IN_DIM  512
#define HDIM    128
#define CDIM    40
#define LAYERS  8
#define NB      196             // scan blocks: ceil(50000/256)

typedef __attribute__((ext_vector_type(8))) short short8;
typedef __attribute__((ext_vector_type(4))) short short4v;
typedef __attribute__((ext_vector_type(4))) float floatx4;
typedef unsigned short ushort_t;

__device__ inline float bf2f(unsigned short u) {
    return __uint_as_float(((unsigned)u) << 16);
}
__device__ inline unsigned short f2bf(float v) {
    __hip_bfloat16 b = __float2bfloat16(v);
    return *reinterpret_cast<unsigned short*>(&b);
}

// ---------------- CSR build ----------------

__global__ void hist_kernel(const int* __restrict__ dst, int* __restrict__ cnt) {
    int i = blockIdx.x * blockDim.x + threadIdx.x;
    if (i < E_EDGES) atomicAdd(&cnt[dst[i]], 1);
}

__global__ void scanA(const int* __restrict__ cnt, int* __restrict__ bsum) {
    __shared__ int sm[256];
    int t = threadIdx.x, i = blockIdx.x * 256 + t;
    sm[t] = (i < N_NODES) ? cnt[i] : 0;
    __syncthreads();
    for (int d = 128; d > 0; d >>= 1) {
        if (t < d) sm[t] += sm[t + d];
        __syncthreads();
    }
    if (t == 0) bsum[blockIdx.x] = sm[0];
}

__global__ void scanB(const int* __restrict__ bsum, int* __restrict__ boff) {
    __shared__ int sm[256];
    int t = threadIdx.x;
    sm[t] = (t < NB) ? bsum[t] : 0;
    __syncthreads();
    for (int d = 1; d < 256; d <<= 1) {
        int v = (t >= d) ? sm[t - d] : 0;
        __syncthreads();
        sm[t] += v;
        __syncthreads();
    }
    if (t < NB) boff[t] = (t > 0) ? sm[t - 1] : 0;
}

__global__ void scanC(const int* __restrict__ cnt, const int* __restrict__ boff,
                      int* __restrict__ row_start, int* __restrict__ cursor) {
    __shared__ int sm[256];
    int t = threadIdx.x, i = blockIdx.x * 256 + t;
    int v = (i < N_NODES) ? cnt[i] : 0;
    sm[t] = v;
    __syncthreads();
    for (int d = 1; d < 256; d <<= 1) {
        int x = (t >= d) ? sm[t - d] : 0;
        __syncthreads();
        sm[t] += x;
        __syncthreads();
    }
    if (i < N_NODES) {
        int incl = boff[blockIdx.x] + sm[t];
        int excl = incl - v;
        row_start[i] = excl;
        cursor[i]    = excl;
        if (i == N_NODES - 1) row_start[N_NODES] = incl;
    }
}

__global__ void scatter_kernel(const int* __restrict__ ei, const float* __restrict__ normA,
                               int* __restrict__ cursor, int2* __restrict__ perm) {
    int i = blockIdx.x * blockDim.x + threadIdx.x;
    if (i >= E_EDGES) return;
    int d = ei[E_EDGES + i];
    int idx = atomicAdd(&cursor[d], 1);
    perm[idx] = make_int2(ei[i], __float_as_int(normA[i]));
}

// ---------------- weight prep: transpose + bf16 convert ----------------

__global__ void prep_weights(const float* __restrict__ W0, const float* __restrict__ convW,
                             const float* __restrict__ W1,
                             ushort_t* __restrict__ Wt0, ushort_t* __restrict__ WtL,
                             ushort_t* __restrict__ Wt1) {
    int i = blockIdx.x * blockDim.x + threadIdx.x;
    if (i < 128 * 512) {
        int n = i >> 9, k = i & 511;
        Wt0[i] = f2bf(W0[k * HDIM + n]);
        return;
    }
    int j = i - 128 * 512;
    if (j < 8 * 128 * 128) {
        int l = j >> 14, rem = j & 16383, n = rem >> 7, k = rem & 127;
        WtL[j] = f2bf(convW[l * 16384 + k * HDIM + n]);
        return;
    }
    int m = j - 8 * 128 * 128;
    if (m < 48 * 128) {
        int n = m >> 7, k = m & 127;
        Wt1[m] = (n < CDIM) ? f2bf(W1[k * CDIM + n]) : (ushort_t)0;
    }
}

// ---------------- fc0: x = relu(F @ W0 + b0) -> h0b (bf16) ----------------
// NO LDS, no barrier. Wave = 16 rows x 128 cols; A-fragments straight from
// global fp32, converted in-register. 4-deep K prefetch (8 float4/lane in
// flight). Block = 4 waves = 64 rows; grid = 782 -> ~12 waves/CU.
// After fc0, x == h0, so only h0b is written (layer 0 reads it as both).

__global__ __launch_bounds__(256)
void fc0_mfma(const float* __restrict__ F, const ushort_t* __restrict__ Wt0,
              const float* __restrict__ b0, ushort_t* __restrict__ h0b) {
    int t = threadIdx.x;
    int wave = t >> 6, lane = t & 63;
    int quad = lane >> 4, l16 = lane & 15;
    int R0 = blockIdx.x * 64 + wave * 16;

    int r = R0 + l16; if (r > N_NODES - 1) r = N_NODES - 1;
    const float* ap = F + (size_t)r * IN_DIM + quad * 8;
    const ushort_t* bbase = Wt0 + (size_t)l16 * IN_DIM + quad * 8;

    floatx4 acc[8];
#pragma unroll
    for (int nt = 0; nt < 8; nt++) acc[nt] = (floatx4){0.f, 0.f, 0.f, 0.f};

    // 4-deep prefetch pipeline: pf[d] holds K-step (ks) with ks % 4 == d
    float4 pf[4][2];
#pragma unroll
    for (int d = 0; d < 4; d++) {
        pf[d][0] = *(const float4*)(ap + d * 32);
        pf[d][1] = *(const float4*)(ap + d * 32 + 4);
    }

#pragma unroll
    for (int ks = 0; ks < 16; ks++) {
        float4 lo = pf[ks & 3][0], hi = pf[ks & 3][1];
        short8 a;
        a[0] = (short)f2bf(lo.x); a[1] = (short)f2bf(lo.y);
        a[2] = (short)f2bf(lo.z); a[3] = (short)f2bf(lo.w);
        a[4] = (short)f2bf(hi.x); a[5] = (short)f2bf(hi.y);
        a[6] = (short)f2bf(hi.z); a[7] = (short)f2bf(hi.w);
        if (ks + 4 < 16) {
            pf[ks & 3][0] = *(const float4*)(ap + (ks + 4) * 32);
            pf[ks & 3][1] = *(const float4*)(ap + (ks + 4) * 32 + 4);
        }
#pragma unroll
        for (int nt = 0; nt < 8; nt++) {
            short8 b = *(const short8*)(bbase + (size_t)nt * 16 * IN_DIM + ks * 32);
            acc[nt] = __builtin_amdgcn_mfma_f32_16x16x32_bf16(a, b, acc[nt], 0, 0, 0);
        }
    }

#pragma unroll
    for (int nt = 0; nt < 8; nt++) {
        int col = nt * 16 + l16;
        float bias = b0[col];
#pragma unroll
        for (int rr = 0; rr < 4; rr++) {
            int row = R0 + quad * 4 + rr;
            float v = acc[nt][rr] + bias;
            v = v > 0.f ? v : 0.f;
            h0b[(size_t)row * HDIM + col] = f2bf(v);
        }
    }
}

// -------- fused layer: sup = 0.9*(A x)+0.1*h0 (into LDS); x' = relu(beta*(sup W)+(1-beta)*sup)
// block = 64 rows, 256 thr / 4 waves. spmm: wave = 16 rows, 4 slots x 16 lanes, 4-deep pipeline.

#define SROW 136   // 128 + 8 pad

__global__ void layer_fused(const int* __restrict__ row_start, const int2* __restrict__ perm,
                            const ushort_t* __restrict__ xb, const ushort_t* __restrict__ h0b,
                            const ushort_t* __restrict__ Wt, ushort_t* __restrict__ X,
                            float beta) {
    __shared__ short sS[64][SROW];   // 17.4 KB
    int t = threadIdx.x;
    int wave = t >> 6, lane = t & 63;
    int slot = lane >> 4, sl = lane & 15;
    int quad = slot, l16 = sl;       // aliases for gemm phase
    int row0 = blockIdx.x * 64;
    int R0 = row0 + wave * 16;

    // this wave's 17 row bounds via lane loads
    int rb = 0;
    if (lane <= 16) {
        int idx = R0 + lane;
        if (idx > N_NODES) idx = N_NODES;
        rb = row_start[idx];
    }

    // ---- spmm phase ----
    for (int r = 0; r < 16; r++) {
        int e0 = __shfl(rb, r), e1 = __shfl(rb, r + 1);
        int grow = R0 + r;
        float acc[8];
#pragma unroll
        for (int c = 0; c < 8; c++) acc[c] = 0.f;

        int ebase = e0 + slot;
        int2 m[4];
        short8 v[4];
#pragma unroll
        for (int d = 0; d < 4; d++) {
            int e = ebase + 4 * d;
            m[d] = (e < e1) ? perm[e] : make_int2(0, 0);
        }
#pragma unroll
        for (int d = 0; d < 4; d++) {
            int e = ebase + 4 * d;
            if (e < e1) v[d] = *(const short8*)(xb + (size_t)m[d].x * HDIM + sl * 8);
        }
        for (int e = ebase; e < e1; e += 16) {
            int2 mn[4];
#pragma unroll
            for (int d = 0; d < 4; d++) {
                int en = e + 16 + 4 * d;
                mn[d] = (en < e1) ? perm[en] : make_int2(0, 0);
            }
#pragma unroll
            for (int d = 0; d < 4; d++) {
                int ec = e + 4 * d;
                if (ec < e1) {
                    float w = __int_as_float(m[d].y);
#pragma unroll
                    for (int c = 0; c < 8; c++) acc[c] += w * bf2f((ushort_t)v[d][c]);
                }
            }
#pragma unroll
            for (int d = 0; d < 4; d++) {
                int en = e + 16 + 4 * d;
                if (en < e1) v[d] = *(const short8*)(xb + (size_t)mn[d].x * HDIM + sl * 8);
                m[d] = mn[d];
            }
        }
#pragma unroll
        for (int c = 0; c < 8; c++) {
            acc[c] += __shfl_xor(acc[c], 16);
            acc[c] += __shfl_xor(acc[c], 32);
        }
        if (slot == 0) {
            short8 o;
            if (grow < N_NODES) {
                short8 h = *(const short8*)(h0b + (size_t)grow * HDIM + sl * 8);
#pragma unroll
                for (int c = 0; c < 8; c++)
                    o[c] = (short)f2bf(0.9f * acc[c] + 0.1f * bf2f((ushort_t)h[c]));
            } else {
#pragma unroll
                for (int c = 0; c < 8; c++) o[c] = 0;
            }
            *(short8*)&sS[wave * 16 + r][sl * 8] = o;
        }
    }
    __syncthreads();

    // ---- gemm phase ----
    short8 afrag[4];
#pragma unroll
    for (int ks = 0; ks < 4; ks++)
        afrag[ks] = *(const short8*)&sS[wave * 16 + l16][ks * 32 + quad * 8];

    floatx4 gacc[8];
#pragma unroll
    for (int nt = 0; nt < 8; nt++) {
        const ushort_t* bp = Wt + (size_t)(nt * 16 + l16) * HDIM + quad * 8;
        floatx4 c = (floatx4){0.f, 0.f, 0.f, 0.f};
#pragma unroll
        for (int ks = 0; ks < 4; ks++) {
            short8 b = *(const short8*)(bp + ks * 32);
            c = __builtin_amdgcn_mfma_f32_16x16x32_bf16(afrag[ks], b, c, 0, 0, 0);
        }
        gacc[nt] = c;
    }
    float g = 1.f - beta;
#pragma unroll
    for (int nt = 0; nt < 8; nt++) {
        int col = nt * 16 + l16;
#pragma unroll
        for (int r = 0; r < 4; r++) {
            int lrow = wave * 16 + quad * 4 + r;
            float s = bf2f((ushort_t)sS[lrow][col]);
            float v = beta * gacc[nt][r] + g * s;
            v = v > 0.f ? v : 0.f;
            X[(size_t)(row0 + lrow) * HDIM + col] = f2bf(v);
        }
    }
}

// ---------------- fc1: out = x @ W1 + b1 (fp32 out), N padded 40->48 ----------------

__global__ void fc1_mfma(const ushort_t* __restrict__ X, const ushort_t* __restrict__ Wt1,
                         const float* __restrict__ b1, float* __restrict__ out) {
    int wave = threadIdx.x >> 6;
    int lane = threadIdx.x & 63;
    int quad = lane >> 4, l16 = lane & 15;
    int row0 = blockIdx.x * 64 + wave * 16;

    int arow = row0 + l16; if (arow > N_NODES - 1) arow = N_NODES - 1;
    const ushort_t* ap = X + (size_t)arow * HDIM + quad * 8;
    short8 afrag[4];
#pragma unroll
    for (int ks = 0; ks < 4; ks++) afrag[ks] = *(const short8*)(ap + ks * 32);

    floatx4 acc[3];
#pragma unroll
    for (int nt = 0; nt < 3; nt++) {
        const ushort_t* bp = Wt1 + (size_t)(nt * 16 + l16) * HDIM + quad * 8;
        floatx4 c = (floatx4){0.f, 0.f, 0.f, 0.f};
#pragma unroll
        for (int ks = 0; ks < 4; ks++) {
            short8 b = *(const short8*)(bp + ks * 32);
            c = __builtin_amdgcn_mfma_f32_16x16x32_bf16(afrag[ks], b, c, 0, 0, 0);
        }
        acc[nt] = c;
    }
#pragma unroll
    for (int nt = 0; nt < 3; nt++) {
        int col = nt * 16 + l16;
        if (col < CDIM) {
            float bias = b1[col];
#pragma unroll
            for (int r = 0; r < 4; r++) {
                int row = row0 + quad * 4 + r;
                if (row < N_NODES)
                    out[(size_t)row * CDIM + col] = acc[nt][r] + bias;
            }
        }
    }
}

// ---------------- launch ----------------

extern "C" void kernel_launch(void* const* d_in, const int* in_sizes, int n_in,
                              void* d_out, int out_size, void* d_ws, size_t ws_size,
                              hipStream_t stream) {
    const float* F     = (const float*)d_in[0];
    const int*   ei    = (const int*)d_in[1];
    const float* normA = (const float*)d_in[2];
    const float* W0    = (const float*)d_in[3];
    const float* b0    = (const float*)d_in[4];
    const float* convW = (const float*)d_in[5];
    const float* W1    = (const float*)d_in[6];
    const float* b1    = (const float*)d_in[7];
    float*       out   = (float*)d_out;

    // workspace layout (bf16 trunk), 16B-aligned
    ushort_t* h0b  = (ushort_t*)d_ws;                     // M_PAD*128
    ushort_t* xab  = h0b + (size_t)M_PAD * HDIM;
    ushort_t* xbb  = xab + (size_t)M_PAD * HDIM;
    ushort_t* Wt0  = xbb + (size_t)M_PAD * HDIM;          // 128*512
    ushort_t* WtL  = Wt0 + 128 * 512;                     // 8*128*128
    ushort_t* Wt1  = WtL + 8 * 128 * 128;                 // 48*128
    int*   row_start = (int*)(Wt1 + 48 * 128);
    int*   cursor    = row_start + (N_NODES + 8);
    int*   cnt       = cursor + (N_NODES + 8);
    int*   bsum      = cnt + (N_NODES + 8);
    int*   boff      = bsum + 256;
    int2*  perm      = (int2*)(boff + 256);               // 8B-aligned

    // CSR build
    hipMemsetAsync(cnt, 0, N_NODES * sizeof(int), stream);
    hist_kernel<<<(E_EDGES + 255) / 256, 256, 0, stream>>>(ei + E_EDGES, cnt);
    scanA<<<NB, 256, 0, stream>>>(cnt, bsum);
    scanB<<<1, 256, 0, stream>>>(bsum, boff);
    scanC<<<NB, 256, 0, stream>>>(cnt, boff, row_start, cursor);
    scatter_kernel<<<(E_EDGES + 255) / 256, 256, 0, stream>>>(ei, normA, cursor, perm);
    prep_weights<<<(128 * 512 + 8 * 128 * 128 + 48 * 128 + 255) / 256, 256, 0, stream>>>(
        W0, convW, W1, Wt0, WtL, Wt1);

    fc0_mfma<<<M_PAD / 64, 256, 0, stream>>>(F, Wt0, b0, h0b);

    // after fc0, x == h0: layer 0 reads h0b as both x and h0
    ushort_t* ping = h0b;
    ushort_t* pong = xab;
    for (int i = 0; i < LAYERS; i++) {
        float beta = logf(0.5f / (float)(i + 1) + 1.0f);
        layer_fused<<<M_PAD / 64, 256, 0, stream>>>(
            row_start, perm, ping, h0b, WtL + (size_t)i * HDIM * HDIM, pong, beta);
        if (i == 0) { ping = xab; pong = xbb; }
        else { ushort_t* tmp = ping; ping = pong; pong = tmp; }
    }
    // layers write: L0->xab, L1->xbb, L2->xab, ... L7->xbb; ping == xbb here
    fc1_mfma<<<M_PAD / 64, 256, 0, stream>>>(ping, Wt1, b1, out);
}

// Round 3
// 732.095 us; speedup vs baseline: 1.1166x; 1.1166x over previous
//
#include <hip/hip_runtime.h>
#include <hip/hip_bf16.h>
#include <math.h>

#define N_NODES 50000
#define M_PAD   50048           // 782 * 64 rows
#define E_EDGES 800000
#define IN_DIM  512
#define HDIM    128
#define CDIM    40
#define LAYERS  8
#define NB      196             // scan blocks: ceil(50000/256)

typedef __attribute__((ext_vector_type(8))) short short8;
typedef __attribute__((ext_vector_type(4))) float floatx4;
typedef unsigned short ushort_t;

__device__ inline float bf2f(unsigned short u) {
    return __uint_as_float(((unsigned)u) << 16);
}
__device__ inline unsigned short f2bf(float v) {
    __hip_bfloat16 b = __float2bfloat16(v);
    return *reinterpret_cast<unsigned short*>(&b);
}

// ---------------- CSR build ----------------

__global__ void hist_kernel(const int* __restrict__ dst, int* __restrict__ cnt) {
    int i = blockIdx.x * blockDim.x + threadIdx.x;
    if (i < E_EDGES) atomicAdd(&cnt[dst[i]], 1);
}

__global__ void scanA(const int* __restrict__ cnt, int* __restrict__ bsum) {
    __shared__ int sm[256];
    int t = threadIdx.x, i = blockIdx.x * 256 + t;
    sm[t] = (i < N_NODES) ? cnt[i] : 0;
    __syncthreads();
    for (int d = 128; d > 0; d >>= 1) {
        if (t < d) sm[t] += sm[t + d];
        __syncthreads();
    }
    if (t == 0) bsum[blockIdx.x] = sm[0];
}

__global__ void scanB(const int* __restrict__ bsum, int* __restrict__ boff) {
    __shared__ int sm[256];
    int t = threadIdx.x;
    sm[t] = (t < NB) ? bsum[t] : 0;
    __syncthreads();
    for (int d = 1; d < 256; d <<= 1) {
        int v = (t >= d) ? sm[t - d] : 0;
        __syncthreads();
        sm[t] += v;
        __syncthreads();
    }
    if (t < NB) boff[t] = (t > 0) ? sm[t - 1] : 0;
}

__global__ void scanC(const int* __restrict__ cnt, const int* __restrict__ boff,
                      int* __restrict__ row_start, int* __restrict__ cursor) {
    __shared__ int sm[256];
    int t = threadIdx.x, i = blockIdx.x * 256 + t;
    int v = (i < N_NODES) ? cnt[i] : 0;
    sm[t] = v;
    __syncthreads();
    for (int d = 1; d < 256; d <<= 1) {
        int x = (t >= d) ? sm[t - d] : 0;
        __syncthreads();
        sm[t] += x;
        __syncthreads();
    }
    if (i < N_NODES) {
        int incl = boff[blockIdx.x] + sm[t];
        int excl = incl - v;
        row_start[i] = excl;
        cursor[i]    = excl;
        if (i == N_NODES - 1) row_start[N_NODES] = incl;
    }
}

__global__ void scatter_kernel(const int* __restrict__ ei, const float* __restrict__ normA,
                               int* __restrict__ cursor, int2* __restrict__ perm) {
    int i = blockIdx.x * blockDim.x + threadIdx.x;
    if (i >= E_EDGES) return;
    int d = ei[E_EDGES + i];
    int idx = atomicAdd(&cursor[d], 1);
    perm[idx] = make_int2(ei[i], __float_as_int(normA[i]));
}

// ---------------- weight prep: transpose + bf16 convert ----------------

__global__ void prep_weights(const float* __restrict__ W0, const float* __restrict__ convW,
                             const float* __restrict__ W1,
                             ushort_t* __restrict__ Wt0, ushort_t* __restrict__ WtL,
                             ushort_t* __restrict__ Wt1) {
    int i = blockIdx.x * blockDim.x + threadIdx.x;
    if (i < 128 * 512) {
        int n = i >> 9, k = i & 511;
        Wt0[i] = f2bf(W0[k * HDIM + n]);
        return;
    }
    int j = i - 128 * 512;
    if (j < 8 * 128 * 128) {
        int l = j >> 14, rem = j & 16383, n = rem >> 7, k = rem & 127;
        WtL[j] = f2bf(convW[l * 16384 + k * HDIM + n]);
        return;
    }
    int m = j - 8 * 128 * 128;
    if (m < 48 * 128) {
        int n = m >> 7, k = m & 127;
        Wt1[m] = (n < CDIM) ? f2bf(W1[k * CDIM + n]) : (ushort_t)0;
    }
}

// ---------------- fc0: x = relu(F @ W0 + b0) -> h0b (bf16) ----------------
// Round-1 structure (best measured): wave = 32 rows x 128 cols, 2-stage K
// pipeline, B loaded once per (nt,ks) feeding 2 MFMAs. Single h0b write.

__global__ __launch_bounds__(256)
void fc0_mfma(const float* __restrict__ F, const ushort_t* __restrict__ Wt0,
              const float* __restrict__ b0, ushort_t* __restrict__ h0b) {
    int t = threadIdx.x;
    int wave = t >> 6, lane = t & 63;
    int quad = lane >> 4, l16 = lane & 15;
    int R0 = blockIdx.x * 128 + wave * 32;

    int r0 = R0 + l16;      if (r0 > N_NODES - 1) r0 = N_NODES - 1;
    int r1 = R0 + 16 + l16; if (r1 > N_NODES - 1) r1 = N_NODES - 1;
    const float* ap0 = F + (size_t)r0 * IN_DIM + quad * 8;
    const float* ap1 = F + (size_t)r1 * IN_DIM + quad * 8;
    const ushort_t* bbase = Wt0 + (size_t)l16 * IN_DIM + quad * 8;

    floatx4 acc0[8], acc1[8];
#pragma unroll
    for (int nt = 0; nt < 8; nt++) {
        acc0[nt] = (floatx4){0.f, 0.f, 0.f, 0.f};
        acc1[nt] = (floatx4){0.f, 0.f, 0.f, 0.f};
    }

    float4 pa00 = *(const float4*)(ap0);
    float4 pa01 = *(const float4*)(ap0 + 4);
    float4 pa10 = *(const float4*)(ap1);
    float4 pa11 = *(const float4*)(ap1 + 4);
    float4 pb00 = *(const float4*)(ap0 + 32);
    float4 pb01 = *(const float4*)(ap0 + 36);
    float4 pb10 = *(const float4*)(ap1 + 32);
    float4 pb11 = *(const float4*)(ap1 + 36);

#pragma unroll
    for (int kk = 0; kk < 16; kk += 2) {
        short8 a0, a1;
        a0[0] = (short)f2bf(pa00.x); a0[1] = (short)f2bf(pa00.y);
        a0[2] = (short)f2bf(pa00.z); a0[3] = (short)f2bf(pa00.w);
        a0[4] = (short)f2bf(pa01.x); a0[5] = (short)f2bf(pa01.y);
        a0[6] = (short)f2bf(pa01.z); a0[7] = (short)f2bf(pa01.w);
        a1[0] = (short)f2bf(pa10.x); a1[1] = (short)f2bf(pa10.y);
        a1[2] = (short)f2bf(pa10.z); a1[3] = (short)f2bf(pa10.w);
        a1[4] = (short)f2bf(pa11.x); a1[5] = (short)f2bf(pa11.y);
        a1[6] = (short)f2bf(pa11.z); a1[7] = (short)f2bf(pa11.w);
        if (kk + 2 < 16) {
            pa00 = *(const float4*)(ap0 + (kk + 2) * 32);
            pa01 = *(const float4*)(ap0 + (kk + 2) * 32 + 4);
            pa10 = *(const float4*)(ap1 + (kk + 2) * 32);
            pa11 = *(const float4*)(ap1 + (kk + 2) * 32 + 4);
        }
#pragma unroll
        for (int nt = 0; nt < 8; nt++) {
            short8 b = *(const short8*)(bbase + (size_t)nt * 16 * IN_DIM + kk * 32);
            acc0[nt] = __builtin_amdgcn_mfma_f32_16x16x32_bf16(a0, b, acc0[nt], 0, 0, 0);
            acc1[nt] = __builtin_amdgcn_mfma_f32_16x16x32_bf16(a1, b, acc1[nt], 0, 0, 0);
        }
        short8 c0, c1;
        c0[0] = (short)f2bf(pb00.x); c0[1] = (short)f2bf(pb00.y);
        c0[2] = (short)f2bf(pb00.z); c0[3] = (short)f2bf(pb00.w);
        c0[4] = (short)f2bf(pb01.x); c0[5] = (short)f2bf(pb01.y);
        c0[6] = (short)f2bf(pb01.z); c0[7] = (short)f2bf(pb01.w);
        c1[0] = (short)f2bf(pb10.x); c1[1] = (short)f2bf(pb10.y);
        c1[2] = (short)f2bf(pb10.z); c1[3] = (short)f2bf(pb10.w);
        c1[4] = (short)f2bf(pb11.x); c1[5] = (short)f2bf(pb11.y);
        c1[6] = (short)f2bf(pb11.z); c1[7] = (short)f2bf(pb11.w);
        if (kk + 3 < 16) {
            pb00 = *(const float4*)(ap0 + (kk + 3) * 32);
            pb01 = *(const float4*)(ap0 + (kk + 3) * 32 + 4);
            pb10 = *(const float4*)(ap1 + (kk + 3) * 32);
            pb11 = *(const float4*)(ap1 + (kk + 3) * 32 + 4);
        }
#pragma unroll
        for (int nt = 0; nt < 8; nt++) {
            short8 b = *(const short8*)(bbase + (size_t)nt * 16 * IN_DIM + (kk + 1) * 32);
            acc0[nt] = __builtin_amdgcn_mfma_f32_16x16x32_bf16(c0, b, acc0[nt], 0, 0, 0);
            acc1[nt] = __builtin_amdgcn_mfma_f32_16x16x32_bf16(c1, b, acc1[nt], 0, 0, 0);
        }
    }

#pragma unroll
    for (int nt = 0; nt < 8; nt++) {
        int col = nt * 16 + l16;
        float bias = b0[col];
#pragma unroll
        for (int r = 0; r < 4; r++) {
            int row = R0 + quad * 4 + r;
            float v = acc0[nt][r] + bias;
            v = v > 0.f ? v : 0.f;
            h0b[(size_t)row * HDIM + col] = f2bf(v);
        }
#pragma unroll
        for (int r = 0; r < 4; r++) {
            int row = R0 + 16 + quad * 4 + r;
            float v = acc1[nt][r] + bias;
            v = v > 0.f ? v : 0.f;
            h0b[(size_t)row * HDIM + col] = f2bf(v);
        }
    }
}

// -------- fused layer: sup = 0.9*(A x)+0.1*h0 (into LDS); x' = relu(beta*(sup W)+(1-beta)*sup)
// block = 64 rows, 256 thr / 4 waves.
// spmm: each 16-lane GROUP owns 4 rows (4 groups/wave concurrent -> serial row
// chain per wave is 4, not 16). One vector load fetches 16 perm entries; edges
// broadcast group-locally via __shfl(.,d,16); invalid edges get w=0/src=0 so
// the inner loop is divergence-free and all 16 gathers/chunk are independent.

#define SROW 136   // 128 + 8 pad

__global__ __launch_bounds__(256)
void layer_fused(const int* __restrict__ row_start, const int2* __restrict__ perm,
                 const ushort_t* __restrict__ xb, const ushort_t* __restrict__ h0b,
                 const ushort_t* __restrict__ Wt, ushort_t* __restrict__ X,
                 float beta) {
    __shared__ short sS[64][SROW];   // 17.4 KB
    int t = threadIdx.x;
    int wave = t >> 6, lane = t & 63;
    int grp = lane >> 4, sl = lane & 15;
    int quad = lane >> 4, l16 = lane & 15;   // gemm aliases
    int row0 = blockIdx.x * 64;
    int G = wave * 4 + grp;                  // block-local group 0..15
    int Rg = row0 + G * 4;                   // 4 rows per group

    // ---- spmm phase: 4 rows per group ----
    for (int r = 0; r < 4; r++) {
        int row = Rg + r;
        int i0 = row < N_NODES ? row : N_NODES;
        int i1 = row + 1 < N_NODES ? row + 1 : N_NODES;
        int e0 = row_start[i0];
        int e1 = row_start[i1];

        float acc[8];
#pragma unroll
        for (int c = 0; c < 8; c++) acc[c] = 0.f;

        for (int chunk = e0; chunk < e1; chunk += 16) {
            int2 pm = make_int2(0, 0);
            if (chunk + sl < e1) pm = perm[chunk + sl];
#pragma unroll
            for (int d = 0; d < 16; d += 4) {
                int   s0 = __shfl(pm.x, d + 0, 16);
                int   s1 = __shfl(pm.x, d + 1, 16);
                int   s2 = __shfl(pm.x, d + 2, 16);
                int   s3 = __shfl(pm.x, d + 3, 16);
                float w0 = __int_as_float(__shfl(pm.y, d + 0, 16));
                float w1 = __int_as_float(__shfl(pm.y, d + 1, 16));
                float w2 = __int_as_float(__shfl(pm.y, d + 2, 16));
                float w3 = __int_as_float(__shfl(pm.y, d + 3, 16));
                short8 v0 = *(const short8*)(xb + (size_t)s0 * HDIM + sl * 8);
                short8 v1 = *(const short8*)(xb + (size_t)s1 * HDIM + sl * 8);
                short8 v2 = *(const short8*)(xb + (size_t)s2 * HDIM + sl * 8);
                short8 v3 = *(const short8*)(xb + (size_t)s3 * HDIM + sl * 8);
#pragma unroll
                for (int c = 0; c < 8; c++) {
                    acc[c] += w0 * bf2f((ushort_t)v0[c]);
                    acc[c] += w1 * bf2f((ushort_t)v1[c]);
                    acc[c] += w2 * bf2f((ushort_t)v2[c]);
                    acc[c] += w3 * bf2f((ushort_t)v3[c]);
                }
            }
        }

        short8 o;
        if (row < N_NODES) {
            short8 h = *(const short8*)(h0b + (size_t)row * HDIM + sl * 8);
#pragma unroll
            for (int c = 0; c < 8; c++)
                o[c] = (short)f2bf(0.9f * acc[c] + 0.1f * bf2f((ushort_t)h[c]));
        } else {
#pragma unroll
            for (int c = 0; c < 8; c++) o[c] = 0;
        }
        *(short8*)&sS[G * 4 + r][sl * 8] = o;
    }
    __syncthreads();

    // ---- gemm phase ----
    short8 afrag[4];
#pragma unroll
    for (int ks = 0; ks < 4; ks++)
        afrag[ks] = *(const short8*)&sS[wave * 16 + l16][ks * 32 + quad * 8];

    floatx4 gacc[8];
#pragma unroll
    for (int nt = 0; nt < 8; nt++) {
        const ushort_t* bp = Wt + (size_t)(nt * 16 + l16) * HDIM + quad * 8;
        floatx4 c = (floatx4){0.f, 0.f, 0.f, 0.f};
#pragma unroll
        for (int ks = 0; ks < 4; ks++) {
            short8 b = *(const short8*)(bp + ks * 32);
            c = __builtin_amdgcn_mfma_f32_16x16x32_bf16(afrag[ks], b, c, 0, 0, 0);
        }
        gacc[nt] = c;
    }
    float g = 1.f - beta;
#pragma unroll
    for (int nt = 0; nt < 8; nt++) {
        int col = nt * 16 + l16;
#pragma unroll
        for (int r = 0; r < 4; r++) {
            int lrow = wave * 16 + quad * 4 + r;
            float s = bf2f((ushort_t)sS[lrow][col]);
            float v = beta * gacc[nt][r] + g * s;
            v = v > 0.f ? v : 0.f;
            X[(size_t)(row0 + lrow) * HDIM + col] = f2bf(v);
        }
    }
}

// ---------------- fc1: out = x @ W1 + b1 (fp32 out), N padded 40->48 ----------------

__global__ void fc1_mfma(const ushort_t* __restrict__ X, const ushort_t* __restrict__ Wt1,
                         const float* __restrict__ b1, float* __restrict__ out) {
    int wave = threadIdx.x >> 6;
    int lane = threadIdx.x & 63;
    int quad = lane >> 4, l16 = lane & 15;
    int row0 = blockIdx.x * 64 + wave * 16;

    int arow = row0 + l16; if (arow > N_NODES - 1) arow = N_NODES - 1;
    const ushort_t* ap = X + (size_t)arow * HDIM + quad * 8;
    short8 afrag[4];
#pragma unroll
    for (int ks = 0; ks < 4; ks++) afrag[ks] = *(const short8*)(ap + ks * 32);

    floatx4 acc[3];
#pragma unroll
    for (int nt = 0; nt < 3; nt++) {
        const ushort_t* bp = Wt1 + (size_t)(nt * 16 + l16) * HDIM + quad * 8;
        floatx4 c = (floatx4){0.f, 0.f, 0.f, 0.f};
#pragma unroll
        for (int ks = 0; ks < 4; ks++) {
            short8 b = *(const short8*)(bp + ks * 32);
            c = __builtin_amdgcn_mfma_f32_16x16x32_bf16(afrag[ks], b, c, 0, 0, 0);
        }
        acc[nt] = c;
    }
#pragma unroll
    for (int nt = 0; nt < 3; nt++) {
        int col = nt * 16 + l16;
        if (col < CDIM) {
            float bias = b1[col];
#pragma unroll
            for (int r = 0; r < 4; r++) {
                int row = row0 + quad * 4 + r;
                if (row < N_NODES)
                    out[(size_t)row * CDIM + col] = acc[nt][r] + bias;
            }
        }
    }
}

// ---------------- launch ----------------

extern "C" void kernel_launch(void* const* d_in, const int* in_sizes, int n_in,
                              void* d_out, int out_size, void* d_ws, size_t ws_size,
                              hipStream_t stream) {
    const float* F     = (const float*)d_in[0];
    const int*   ei    = (const int*)d_in[1];
    const float* normA = (const float*)d_in[2];
    const float* W0    = (const float*)d_in[3];
    const float* b0    = (const float*)d_in[4];
    const float* convW = (const float*)d_in[5];
    const float* W1    = (const float*)d_in[6];
    const float* b1    = (const float*)d_in[7];
    float*       out   = (float*)d_out;

    // workspace layout (bf16 trunk), 16B-aligned
    ushort_t* h0b  = (ushort_t*)d_ws;                     // M_PAD*128
    ushort_t* xab  = h0b + (size_t)M_PAD * HDIM;
    ushort_t* xbb  = xab + (size_t)M_PAD * HDIM;
    ushort_t* Wt0  = xbb + (size_t)M_PAD * HDIM;          // 128*512
    ushort_t* WtL  = Wt0 + 128 * 512;                     // 8*128*128
    ushort_t* Wt1  = WtL + 8 * 128 * 128;                 // 48*128
    int*   row_start = (int*)(Wt1 + 48 * 128);
    int*   cursor    = row_start + (N_NODES + 8);
    int*   cnt       = cursor + (N_NODES + 8);
    int*   bsum      = cnt + (N_NODES + 8);
    int*   boff      = bsum + 256;
    int2*  perm      = (int2*)(boff + 256);               // 8B-aligned

    // CSR build
    hipMemsetAsync(cnt, 0, N_NODES * sizeof(int), stream);
    hist_kernel<<<(E_EDGES + 255) / 256, 256, 0, stream>>>(ei + E_EDGES, cnt);
    scanA<<<NB, 256, 0, stream>>>(cnt, bsum);
    scanB<<<1, 256, 0, stream>>>(bsum, boff);
    scanC<<<NB, 256, 0, stream>>>(cnt, boff, row_start, cursor);
    scatter_kernel<<<(E_EDGES + 255) / 256, 256, 0, stream>>>(ei, normA, cursor, perm);
    prep_weights<<<(128 * 512 + 8 * 128 * 128 + 48 * 128 + 255) / 256, 256, 0, stream>>>(
        W0, convW, W1, Wt0, WtL, Wt1);

    fc0_mfma<<<M_PAD / 128, 256, 0, stream>>>(F, Wt0, b0, h0b);

    // after fc0, x == h0: layer 0 reads h0b as both x and h0
    ushort_t* ping = h0b;
    ushort_t* pong = xab;
    for (int i = 0; i < LAYERS; i++) {
        float beta = logf(0.5f / (float)(i + 1) + 1.0f);
        layer_fused<<<M_PAD / 64, 256, 0, stream>>>(
            row_start, perm, ping, h0b, WtL + (size_t)i * HDIM * HDIM, pong, beta);
        if (i == 0) { ping = xab; pong = xbb; }
        else { ushort_t* tmp = ping; ping = pong; pong = tmp; }
    }
    // L0->xab, L1->xbb, ..., L7->xbb; ping == xbb here
    fc1_mfma<<<M_PAD / 64, 256, 0, stream>>>(ping, Wt1, b1, out);
}